// Round 7
// baseline (214.348 us; speedup 1.0000x reference)
//
#include <hip/hip_runtime.h>
#include <math.h>

#define ALPHA_C (-0.01f)
#define BLOCKT 320     // 5 waves; wave v = wave-uniform segment role
#define NWIN 127       // windows resolved per workgroup
#define NB 640         // 50-blocks covered per workgroup (2 per thread)
#define SROW 52        // padded S half-row stride (208 B, 16B-aligned rows)

__global__ __launch_bounds__(BLOCKT)
void softmin_dtw_kernel(const float* __restrict__ x, const float* __restrict__ S,
                        float* __restrict__ out, long long Q, int W,
                        float inv_W) {
  __shared__ __align__(16) float sS[10 * SROW];  // rows 0-4: S[j][0:50], 5-9: S[j][50:100]
  __shared__ float sYY[5];
  __shared__ __align__(16) float4 exch[NB];      // {sq, B0, B1, B2} per 50-block
  __shared__ __align__(16) float4 cw[NWIN * 5];  // {xx, xy[i][i-1], xy[i][i], xy[i][i+1]}

  const int tid = threadIdx.x;

  // ---- Stage S into duplicated, padded half-rows ----
  for (int t = tid; t < 10 * SROW; t += BLOCKT) {
    const int r = t / SROW, c = t % SROW;
    float vv = 0.f;
    if (c < 50) vv = (r < 5) ? S[100 * r + c] : S[100 * (r - 5) + 50 + c];
    sS[t] = vv;
  }
  if (tid < 5) {
    float a = 0.f;
    #pragma unroll 10
    for (int s = 0; s < 100; s += 2) {
      const float2 vv = *reinterpret_cast<const float2*>(&S[tid * 100 + s]);
      a = fmaf(vv.x, vv.x, fmaf(vv.y, vv.y, a));
    }
    sYY[tid] = a;
  }
  __syncthreads();

  // ---- Roles: wave-uniform; two 50-blocks per thread share them ----
  const int v = __builtin_amdgcn_readfirstlane(tid >> 6);  // wave 0..4
  const int l = tid & 63;
  const int b0 = 5 * l + v;        // stream-0 block (in [0,320))
  const int b1 = b0 + 320;         // stream-1 block (same residue mod 5)
  const int i0 = (3 * v) % 5;      // first-half segment role
  const int i1 = (i0 + 2) % 5;     // second-half segment role
  const float* __restrict__ SA0 = &sS[SROW * (i0 > 0 ? i0 - 1 : 0)];
  const float* __restrict__ SA1 = &sS[SROW * i0];
  const float* __restrict__ SA2 = &sS[SROW * (i0 < 4 ? i0 + 1 : 4)];
  const float* __restrict__ SB0 = &sS[SROW * (5 + (i1 > 0 ? i1 - 1 : 0))];
  const float* __restrict__ SB1 = &sS[SROW * (5 + i1)];
  const float* __restrict__ SB2 = &sS[SROW * (5 + (i1 < 4 ? i1 + 1 : 4))];

  // ---- x addressing: 16B-aligned rolling loads, one shift for both streams ----
  const long long base = 31750LL * blockIdx.x;   // NWIN*250
  const long long e0 = base + 50LL * b0;
  long long Aa = e0 & ~3LL;
  if (Aa > Q - 56) Aa = (Q - 56) & ~3LL;         // clamped threads feed only w>=W
  long long Ab = Aa + 16000;                     // stream-1 base (same alignment)
  if (Ab > Q - 56) Ab = (Q - 56) & ~3LL;
  const int sh = (int)(e0 - Aa);                 // 0 or 2 for unclamped threads

  float4 c0a = *reinterpret_cast<const float4*>(&x[Aa]);
  float4 n0a = *reinterpret_cast<const float4*>(&x[Aa + 4]);
  float4 c0b = *reinterpret_cast<const float4*>(&x[Ab]);
  float4 n0b = *reinterpret_cast<const float4*>(&x[Ab + 4]);

  float sqa = 0.f, A0a = 0.f, A1a = 0.f, A2a = 0.f, B0a = 0.f, B1a = 0.f, B2a = 0.f;
  float sqb = 0.f, A0b = 0.f, A1b = 0.f, A2b = 0.f, B0b = 0.f, B1b = 0.f, B2b = 0.f;

  #pragma unroll
  for (int k = 0; k < 12; ++k) {
    const float4 fa = *reinterpret_cast<const float4*>(&x[Aa + 4 * k + 8]);
    const float4 fb = *reinterpret_cast<const float4*>(&x[Ab + 4 * k + 8]);

    float4 qa, qb;
    qa.x = sh ? c0a.z : c0a.x;  qa.y = sh ? c0a.w : c0a.y;
    qa.z = sh ? n0a.x : c0a.z;  qa.w = sh ? n0a.y : c0a.w;
    qb.x = sh ? c0b.z : c0b.x;  qb.y = sh ? c0b.w : c0b.y;
    qb.z = sh ? n0b.x : c0b.z;  qb.w = sh ? n0b.y : c0b.w;

    const int t4 = 4 * k;
    sqa = fmaf(qa.x, qa.x, fmaf(qa.y, qa.y, fmaf(qa.z, qa.z, fmaf(qa.w, qa.w, sqa))));
    sqb = fmaf(qb.x, qb.x, fmaf(qb.y, qb.y, fmaf(qb.z, qb.z, fmaf(qb.w, qb.w, sqb))));
    float4 y;
    y = *reinterpret_cast<const float4*>(&SA0[t4]);
    A0a = fmaf(qa.x, y.x, fmaf(qa.y, y.y, fmaf(qa.z, y.z, fmaf(qa.w, y.w, A0a))));
    A0b = fmaf(qb.x, y.x, fmaf(qb.y, y.y, fmaf(qb.z, y.z, fmaf(qb.w, y.w, A0b))));
    y = *reinterpret_cast<const float4*>(&SA1[t4]);
    A1a = fmaf(qa.x, y.x, fmaf(qa.y, y.y, fmaf(qa.z, y.z, fmaf(qa.w, y.w, A1a))));
    A1b = fmaf(qb.x, y.x, fmaf(qb.y, y.y, fmaf(qb.z, y.z, fmaf(qb.w, y.w, A1b))));
    y = *reinterpret_cast<const float4*>(&SA2[t4]);
    A2a = fmaf(qa.x, y.x, fmaf(qa.y, y.y, fmaf(qa.z, y.z, fmaf(qa.w, y.w, A2a))));
    A2b = fmaf(qb.x, y.x, fmaf(qb.y, y.y, fmaf(qb.z, y.z, fmaf(qb.w, y.w, A2b))));
    y = *reinterpret_cast<const float4*>(&SB0[t4]);
    B0a = fmaf(qa.x, y.x, fmaf(qa.y, y.y, fmaf(qa.z, y.z, fmaf(qa.w, y.w, B0a))));
    B0b = fmaf(qb.x, y.x, fmaf(qb.y, y.y, fmaf(qb.z, y.z, fmaf(qb.w, y.w, B0b))));
    y = *reinterpret_cast<const float4*>(&SB1[t4]);
    B1a = fmaf(qa.x, y.x, fmaf(qa.y, y.y, fmaf(qa.z, y.z, fmaf(qa.w, y.w, B1a))));
    B1b = fmaf(qb.x, y.x, fmaf(qb.y, y.y, fmaf(qb.z, y.z, fmaf(qb.w, y.w, B1b))));
    y = *reinterpret_cast<const float4*>(&SB2[t4]);
    B2a = fmaf(qa.x, y.x, fmaf(qa.y, y.y, fmaf(qa.z, y.z, fmaf(qa.w, y.w, B2a))));
    B2b = fmaf(qb.x, y.x, fmaf(qb.y, y.y, fmaf(qb.z, y.z, fmaf(qb.w, y.w, B2b))));

    c0a = n0a; n0a = fa;
    c0b = n0b; n0b = fb;
  }
  {  // tail columns 48,49 (both parities live in r12 = current c0*)
    const float qax = sh ? c0a.z : c0a.x, qay = sh ? c0a.w : c0a.y;
    const float qbx = sh ? c0b.z : c0b.x, qby = sh ? c0b.w : c0b.y;
    sqa = fmaf(qax, qax, fmaf(qay, qay, sqa));
    sqb = fmaf(qbx, qbx, fmaf(qby, qby, sqb));
    float2 y;
    y = *reinterpret_cast<const float2*>(&SA0[48]);
    A0a = fmaf(qax, y.x, fmaf(qay, y.y, A0a));
    A0b = fmaf(qbx, y.x, fmaf(qby, y.y, A0b));
    y = *reinterpret_cast<const float2*>(&SA1[48]);
    A1a = fmaf(qax, y.x, fmaf(qay, y.y, A1a));
    A1b = fmaf(qbx, y.x, fmaf(qby, y.y, A1b));
    y = *reinterpret_cast<const float2*>(&SA2[48]);
    A2a = fmaf(qax, y.x, fmaf(qay, y.y, A2a));
    A2b = fmaf(qbx, y.x, fmaf(qby, y.y, A2b));
    y = *reinterpret_cast<const float2*>(&SB0[48]);
    B0a = fmaf(qax, y.x, fmaf(qay, y.y, B0a));
    B0b = fmaf(qbx, y.x, fmaf(qby, y.y, B0b));
    y = *reinterpret_cast<const float2*>(&SB1[48]);
    B1a = fmaf(qax, y.x, fmaf(qay, y.y, B1a));
    B1b = fmaf(qbx, y.x, fmaf(qby, y.y, B1b));
    y = *reinterpret_cast<const float2*>(&SB2[48]);
    B2a = fmaf(qax, y.x, fmaf(qay, y.y, B2a));
    B2b = fmaf(qbx, y.x, fmaf(qby, y.y, B2b));
  }

  // ---- Neighbor combine via LDS (global-b indexed; validated layout) ----
  {
    float4 ex;
    ex.x = sqa; ex.y = B0a; ex.z = B1a; ex.w = B2a;
    exch[b0] = ex;
    ex.x = sqb; ex.y = B0b; ex.z = B1b; ex.w = B2b;
    exch[b1] = ex;
  }
  __syncthreads();
  {
    const int w0 = (b0 - 2 * i0) / 5;  // exact division by construction
    if (w0 >= 0 && w0 < NWIN) {
      const float4 nx = exch[b0 + 1];
      float4 c;
      c.x = sqa + nx.x; c.y = A0a + nx.y; c.z = A1a + nx.z; c.w = A2a + nx.w;
      cw[w0 * 5 + i0] = c;
    }
    const int w1 = (b1 - 2 * i0) / 5;  // = w0 + 64
    if (w1 >= 0 && w1 < NWIN) {        // b1=639 -> w1=127 skipped, exch[640] never read
      const float4 nx = exch[b1 + 1];
      float4 c;
      c.x = sqb + nx.x; c.y = A0b + nx.y; c.z = A1b + nx.z; c.w = A2b + nx.w;
      cw[w1 * 5 + i0] = c;
    }
  }
  __syncthreads();

  // ---- DTW + exp per window (threads 0..126 = waves 0,1) ----
  float xi = 0.f;
  if (tid < NWIN) {
    const long long w = (long long)blockIdx.x * NWIN + tid;
    if (w < W) {
      const float yy0 = sYY[0], yy1 = sYY[1], yy2 = sYY[2], yy3 = sYY[3],
                  yy4 = sYY[4];
      const float4 c0 = cw[tid * 5 + 0];
      const float4 c1 = cw[tid * 5 + 1];
      const float4 c2 = cw[tid * 5 + 2];
      const float4 c3 = cw[tid * 5 + 3];
      const float4 c4 = cw[tid * 5 + 4];

      const float C00 = c0.x + yy0 - 2.f * c0.z;
      const float C01 = c0.x + yy1 - 2.f * c0.w;
      const float C10 = c1.x + yy0 - 2.f * c1.y;
      const float C11 = c1.x + yy1 - 2.f * c1.z;
      const float C12 = c1.x + yy2 - 2.f * c1.w;
      const float C21 = c2.x + yy1 - 2.f * c2.y;
      const float C22 = c2.x + yy2 - 2.f * c2.z;
      const float C23 = c2.x + yy3 - 2.f * c2.w;
      const float C32 = c3.x + yy2 - 2.f * c3.y;
      const float C33 = c3.x + yy3 - 2.f * c3.z;
      const float C34 = c3.x + yy4 - 2.f * c3.w;
      const float C43 = c4.x + yy3 - 2.f * c4.y;
      const float C44 = c4.x + yy4 - 2.f * c4.z;

      const float c11v = C00;
      const float c12v = C01 + c11v;
      const float c21v = C10 + c11v;
      const float c22v = C11 + fminf(fminf(c12v, c21v), c11v);
      const float c23v = C12 + fminf(c22v, c12v);
      const float c32v = C21 + fminf(c22v, c21v);
      const float c33v = C22 + fminf(fminf(c23v, c32v), c22v);
      const float c34v = C23 + fminf(c33v, c23v);
      const float c43v = C32 + fminf(c33v, c32v);
      const float c44v = C33 + fminf(fminf(c34v, c43v), c33v);
      const float c45v = C34 + fminf(c44v, c34v);
      const float c54v = C43 + fminf(c44v, c43v);
      const float c55v = C44 + fminf(fminf(c45v, c54v), c44v);

      xi = expf(ALPHA_C * sqrtf(fmaxf(c55v, 0.f)));
    }
  }

  // Waves 0 and 1 hold nonzero xi; reduce per wave, one atomic each
  if (tid < 128) {
    #pragma unroll
    for (int off = 32; off > 0; off >>= 1) xi += __shfl_down(xi, off);
    if ((tid & 63) == 0) atomicAdd(out, xi * inv_W);
  }
}

extern "C" void kernel_launch(void* const* d_in, const int* in_sizes, int n_in,
                              void* d_out, int out_size, void* d_ws, size_t ws_size,
                              hipStream_t stream) {
  const float* x = (const float*)d_in[0];
  const float* S = (const float*)d_in[1];
  float* out = (float*)d_out;

  const long long Q = in_sizes[0];
  const int L = in_sizes[1];   // 500
  const int step = L / 2;      // 250
  const long long n = Q - L;
  const int W = (int)((n + step - 1) / step);  // 79998

  hipMemsetAsync(out, 0, sizeof(float), stream);

  const int blocks = (W + NWIN - 1) / NWIN;  // 630
  softmin_dtw_kernel<<<blocks, BLOCKT, 0, stream>>>(x, S, out, Q, W,
                                                    1.0f / (float)W);
}

// Round 8
// 140.370 us; speedup vs baseline: 1.5270x; 1.5270x over previous
//
#include <hip/hip_runtime.h>
#include <math.h>

#define ALPHA_C (-0.01f)
#define BLOCK 256
#define NWIN 50           // windows resolved per WG
#define NBLK 256          // 50-blocks staged per WG (50*5 + 6, rounded to 256)
#define SU 36             // x row stride in uints (144 B: 16B-aligned, 2-way banks)

typedef __attribute__((ext_vector_type(8))) short short8;
typedef __attribute__((ext_vector_type(4))) float f32x4;

__global__ __launch_bounds__(BLOCK)
void softmin_dtw_kernel(const float* __restrict__ x, const float* __restrict__ S,
                        float* __restrict__ out, long long Q, int W,
                        float inv_W) {
  __shared__ uint sXbf[NBLK * SU];   // bf16 x-blocks: row m = block m, 64 k-slots
  __shared__ float sD[NBLK * 10];    // D[b][r] = dot(xblk b, S half-row r)
  __shared__ float sxx[NBLK];
  __shared__ float sYY[5];

  const int tid = threadIdx.x;
  const long long base = 12500LL * blockIdx.x;  // NWIN*250 floats per WG

  const int n = tid & 15;        // MFMA n / m-within-tile index
  const int q = (tid >> 4) & 3;  // MFMA quad

  // ---- B fragments: S half-rows as bf16 (n>=10 or k>=50 -> 0) ----
  short8 bf0, bf1;
  #pragma unroll
  for (int j = 0; j < 8; ++j) {
    const int k0 = 8 * q + j;
    const int k1 = 32 + 8 * q + j;
    float v0 = 0.f, v1 = 0.f;
    if (n < 10) {
      v0 = (n < 5) ? S[100 * n + k0] : S[100 * (n - 5) + 50 + k0];
      if (k1 < 50) v1 = (n < 5) ? S[100 * n + k1] : S[100 * (n - 5) + 50 + k1];
    }
    bf0[j] = (short)(__float_as_uint(v0) >> 16);
    bf1[j] = (short)(__float_as_uint(v1) >> 16);
  }

  // ---- yy[j] (fp32, from global) ----
  if (tid < 5) {
    float a = 0.f;
    #pragma unroll 10
    for (int s = 0; s < 100; s += 2) {
      const float2 vv = *reinterpret_cast<const float2*>(&S[tid * 100 + s]);
      a = fmaf(vv.x, vv.x, fmaf(vv.y, vv.y, a));
    }
    sYY[tid] = a;
  }

  // ---- Zero k=50..63 pad of own row (kills A-side garbage incl. NaNs) ----
  {
    uint* rp = &sXbf[tid * SU];
    rp[25] = 0u;
    #pragma unroll
    for (int z = 26; z < 36; z += 2)
      *reinterpret_cast<uint2*>(&rp[z]) = make_uint2(0u, 0u);  // byte 104+8k: 8B-aligned
  }

  // ---- Stage x: coalesced float4, truncate-pack to bf16 pairs ----
  int m = (4 * tid) / 50;
  int e = (4 * tid) % 50;   // even always
  #pragma unroll
  for (int r = 0; r < 13; ++r) {
    const int idx = r * BLOCK + tid;
    if (idx < 3200) {
      const long long g = base + 4LL * idx;
      float4 v;
      if (g + 4 <= Q) {
        v = *reinterpret_cast<const float4*>(&x[g]);
      } else {
        v.x = (g     < Q) ? x[g]     : 0.f;
        v.y = (g + 1 < Q) ? x[g + 1] : 0.f;
        v.z = (g + 2 < Q) ? x[g + 2] : 0.f;
        v.w = (g + 3 < Q) ? x[g + 3] : 0.f;
      }
      // [hi16(f1) : hi16(f0)] -> two bf16 in memory order
      const uint u0 = __builtin_amdgcn_perm(__float_as_uint(v.y),
                                            __float_as_uint(v.x), 0x07060302u);
      const uint u1 = __builtin_amdgcn_perm(__float_as_uint(v.w),
                                            __float_as_uint(v.z), 0x07060302u);
      sXbf[m * SU + (e >> 1)] = u0;
      sXbf[(e == 48) ? ((m + 1) * SU) : (m * SU + (e >> 1) + 1)] = u1;
    }
    // advance by 1024 elements = 20 blocks + 24 elems
    e += 24; m += 20;
    if (e >= 50) { e -= 50; ++m; }
  }
  __syncthreads();

  // ---- xx per block (unpack bf16, fp32 accumulate) ----
  {
    const uint* rp = &sXbf[tid * SU];
    float a = 0.f;
    #pragma unroll
    for (int r = 0; r < 6; ++r) {
      const uint4 u = *reinterpret_cast<const uint4*>(&rp[4 * r]);
      const uint uu[4] = {u.x, u.y, u.z, u.w};
      #pragma unroll
      for (int c = 0; c < 4; ++c) {
        const float lo = __uint_as_float(uu[c] << 16);
        const float hi = __uint_as_float(uu[c] & 0xffff0000u);
        a = fmaf(lo, lo, fmaf(hi, hi, a));
      }
    }
    const uint ut = rp[24];
    const float lo = __uint_as_float(ut << 16);
    const float hi = __uint_as_float(ut & 0xffff0000u);
    a = fmaf(lo, lo, fmaf(hi, hi, a));
    sxx[tid] = a;
  }

  // ---- MFMA: wave wv does tiles 4wv..4wv+3 (16 blocks x 16 rows each) ----
  {
    const int wv = tid >> 6;
    #pragma unroll
    for (int tt = 0; tt < 4; ++tt) {
      const int tile = wv * 4 + tt;
      const int mg = tile * 16 + n;
      const short8 a0 = *reinterpret_cast<const short8*>(&sXbf[mg * SU + 4 * q]);
      const short8 a1 =
          *reinterpret_cast<const short8*>(&sXbf[mg * SU + 16 + 4 * q]);
      f32x4 acc = {0.f, 0.f, 0.f, 0.f};
      acc = __builtin_amdgcn_mfma_f32_16x16x32_bf16(a0, bf0, acc, 0, 0, 0);
      acc = __builtin_amdgcn_mfma_f32_16x16x32_bf16(a1, bf1, acc, 0, 0, 0);
      if (n < 10) {
        #pragma unroll
        for (int reg = 0; reg < 4; ++reg)
          sD[(tile * 16 + q * 4 + reg) * 10 + n] = acc[reg];  // row=(l>>4)*4+reg, col=l&15
      }
    }
  }
  __syncthreads();

  // ---- DTW + exp per window (threads 0..49) ----
  float xi = 0.f;
  if (tid < NWIN) {
    const long long w = (long long)blockIdx.x * NWIN + tid;
    if (w < W) {
      float xxv[5], xyM[5], xy0v[5], xyP[5];
      #pragma unroll
      for (int i = 0; i < 5; ++i) {
        const int b = 5 * tid + 2 * i;
        xxv[i] = sxx[b] + sxx[b + 1];
        const float* Da = &sD[b * 10];           // first-half dots (rows 0-4)
        const float* Db = &sD[(b + 1) * 10 + 5]; // second-half dots (rows 5-9)
        if (i > 0) xyM[i] = Da[i - 1] + Db[i - 1];
        xy0v[i] = Da[i] + Db[i];
        if (i < 4) xyP[i] = Da[i + 1] + Db[i + 1];
      }
      const float yy0 = sYY[0], yy1 = sYY[1], yy2 = sYY[2], yy3 = sYY[3],
                  yy4 = sYY[4];
      const float C00 = xxv[0] + yy0 - 2.f * xy0v[0];
      const float C01 = xxv[0] + yy1 - 2.f * xyP[0];
      const float C10 = xxv[1] + yy0 - 2.f * xyM[1];
      const float C11 = xxv[1] + yy1 - 2.f * xy0v[1];
      const float C12 = xxv[1] + yy2 - 2.f * xyP[1];
      const float C21 = xxv[2] + yy1 - 2.f * xyM[2];
      const float C22 = xxv[2] + yy2 - 2.f * xy0v[2];
      const float C23 = xxv[2] + yy3 - 2.f * xyP[2];
      const float C32 = xxv[3] + yy2 - 2.f * xyM[3];
      const float C33 = xxv[3] + yy3 - 2.f * xy0v[3];
      const float C34 = xxv[3] + yy4 - 2.f * xyP[3];
      const float C43 = xxv[4] + yy3 - 2.f * xyM[4];
      const float C44 = xxv[4] + yy4 - 2.f * xy0v[4];

      const float c11v = C00;
      const float c12v = C01 + c11v;
      const float c21v = C10 + c11v;
      const float c22v = C11 + fminf(fminf(c12v, c21v), c11v);
      const float c23v = C12 + fminf(c22v, c12v);
      const float c32v = C21 + fminf(c22v, c21v);
      const float c33v = C22 + fminf(fminf(c23v, c32v), c22v);
      const float c34v = C23 + fminf(c33v, c23v);
      const float c43v = C32 + fminf(c33v, c32v);
      const float c44v = C33 + fminf(fminf(c34v, c43v), c33v);
      const float c45v = C34 + fminf(c44v, c34v);
      const float c54v = C43 + fminf(c44v, c43v);
      const float c55v = C44 + fminf(fminf(c45v, c54v), c44v);

      xi = expf(ALPHA_C * sqrtf(fmaxf(c55v, 0.f)));
    }
  }

  if (tid < 64) {
    #pragma unroll
    for (int off = 32; off > 0; off >>= 1) xi += __shfl_down(xi, off);
    if (tid == 0) atomicAdd(out, xi * inv_W);
  }
}

extern "C" void kernel_launch(void* const* d_in, const int* in_sizes, int n_in,
                              void* d_out, int out_size, void* d_ws, size_t ws_size,
                              hipStream_t stream) {
  const float* x = (const float*)d_in[0];
  const float* S = (const float*)d_in[1];
  float* out = (float*)d_out;

  const long long Q = in_sizes[0];
  const int L = in_sizes[1];   // 500
  const int step = L / 2;      // 250
  const long long n = Q - L;
  const int W = (int)((n + step - 1) / step);  // 79998

  hipMemsetAsync(out, 0, sizeof(float), stream);

  const int blocks = (W + NWIN - 1) / NWIN;  // 1600
  softmin_dtw_kernel<<<blocks, BLOCK, 0, stream>>>(x, S, out, Q, W,
                                                   1.0f / (float)W);
}